// Round 7
// baseline (555.503 us; speedup 1.0000x reference)
//
#include <hip/hip_runtime.h>

#define N_NODES  50000
#define N_ROWS   50048        // padded row count (multiple of 64)
#define N_EDGES  1600000
#define N_GRAPHS 2048
#define DIM      133
#define HSTR     136          // bf16 row stride for gemm-output / agg-input buffers
#define YSTR     160          // bf16 row stride for gemm-input buffers (K padded to 160)
#define EPSV     1e-5f
#define NRANGE   8
#define RSPAN    6250         // N_NODES / NRANGE

typedef __attribute__((ext_vector_type(8))) short bf16x8;
typedef __attribute__((ext_vector_type(4))) float f32x4;

// ---- bf16 helpers (raw ushort; bf16 = top 16 bits of fp32) ----
__device__ __forceinline__ float blo(unsigned u) { return __uint_as_float(u << 16); }
__device__ __forceinline__ float bhi(unsigned u) { return __uint_as_float(u & 0xFFFF0000u); }
__device__ __forceinline__ unsigned short f2bf(float x) {
    unsigned v = __float_as_uint(x);
    return (unsigned short)((v + 0x7FFFu + ((v >> 16) & 1u)) >> 16);  // RNE
}
__device__ __forceinline__ unsigned packbf(float a, float b) {
    return (unsigned)f2bf(a) | ((unsigned)f2bf(b) << 16);
}

// ---------------- setup kernels ----------------

__global__ __launch_bounds__(256) void k_count(const int* __restrict__ col,
                                               const int* __restrict__ batch,
                                               int* __restrict__ deg,
                                               int* __restrict__ cnt)
{
    int idx = blockIdx.x * 256 + threadIdx.x;
    if (idx < N_EDGES) atomicAdd(&deg[col[idx]], 1);
    if (idx < N_NODES) atomicAdd(&cnt[batch[idx]], 1);
}

__global__ __launch_bounds__(256) void k_finalize(const int* __restrict__ deg,
                                                  const int* __restrict__ cnt,
                                                  float* __restrict__ dinv,
                                                  float* __restrict__ inv_cnt)
{
    int idx = blockIdx.x * 256 + threadIdx.x;
    if (idx < N_NODES)  dinv[idx]    = rsqrtf((float)deg[idx] + 1.0f); // +1 self loop
    if (idx < N_GRAPHS) inv_cnt[idx] = 1.0f / (float)max(cnt[idx], 1);
}

__global__ __launch_bounds__(256) void k_scan1(const int* __restrict__ deg,
                                               int* __restrict__ offs,
                                               int* __restrict__ bsum)
{
    __shared__ int sd[256];
    int t = threadIdx.x;
    int idx = blockIdx.x * 256 + t;
    int v = (idx < N_NODES) ? deg[idx] : 0;
    sd[t] = v; __syncthreads();
    for (int o = 1; o < 256; o <<= 1) {
        int add = (t >= o) ? sd[t - o] : 0;
        __syncthreads();
        sd[t] += add;
        __syncthreads();
    }
    if (idx < N_NODES) offs[idx] = sd[t] - v;
    if (t == 255) bsum[blockIdx.x] = sd[255];
}

__global__ __launch_bounds__(256) void k_scan2(const int* __restrict__ bsum,
                                               int* __restrict__ boff, int nb)
{
    __shared__ int sd[256];
    int t = threadIdx.x;
    int v = (t < nb) ? bsum[t] : 0;
    sd[t] = v; __syncthreads();
    for (int o = 1; o < 256; o <<= 1) {
        int add = (t >= o) ? sd[t - o] : 0;
        __syncthreads();
        sd[t] += add;
        __syncthreads();
    }
    boff[t] = sd[t] - v;
}

__global__ __launch_bounds__(256) void k_scan3(int* __restrict__ offs,
                                               const int* __restrict__ boff)
{
    int idx = blockIdx.x * 256 + threadIdx.x;
    if (idx < N_NODES)       offs[idx] += boff[blockIdx.x];
    else if (idx == N_NODES) offs[N_NODES] = N_EDGES;
}

// Range-partitioned CSR fill: blocks with (blockIdx&7)==r only handle dests in
// range r (6250 nodes, 400 KB csr sub-region) -> scatter stays hot in one L2
// (blockIdx%8 ~ XCD round-robin heuristic; correctness doesn't depend on it).
__global__ __launch_bounds__(256) void k_fill(const int* __restrict__ row,
                                              const int* __restrict__ col,
                                              const int* __restrict__ offs,
                                              int* __restrict__ cursor,
                                              unsigned short* __restrict__ csr_src)
{
    int r  = blockIdx.x & (NRANGE - 1);
    int bi = blockIdx.x >> 3;
    int nb = gridDim.x >> 3;
    int lo = r * RSPAN, hi = lo + RSPAN;
    for (int e = bi * 256 + threadIdx.x; e < N_EDGES; e += nb * 256) {
        int c = col[e];
        if (c >= lo && c < hi) {
            int p = offs[c] + atomicAdd(&cursor[c], 1);
            csr_src[p] = (unsigned short)row[e];
        }
    }
}

// ---- pack W (fp32 [133][133], W[k][n]) into MFMA B-fragment layout ----
__global__ __launch_bounds__(256) void k_w2bf(const float* __restrict__ W,
                                              unsigned short* __restrict__ Wbf)
{
    int idx = blockIdx.x * 256 + threadIdx.x;          // 9*5*64*8 = 23040
    if (idx >= 23040) return;
    int j    = idx & 7;
    int lane = (idx >> 3) & 63;
    int kc   = (idx >> 9) % 5;
    int t    = idx / (8 * 64 * 5);
    int k = kc * 32 + (lane >> 4) * 8 + j;
    int n = t * 16 + (lane & 15);
    float v = (k < DIM && n < DIM) ? W[k * DIM + n] : 0.f;
    Wbf[idx] = f2bf(v);
}

// ---- convert x fp32 [N][133] -> bf16 [N][160] with zero K-padding ----
__global__ __launch_bounds__(256) void k_x2bf(const float* __restrict__ x,
                                              unsigned* __restrict__ Abf) // uint = 2 bf16
{
    int idx = blockIdx.x * 256 + threadIdx.x;          // N_NODES * 80
    if (idx >= N_NODES * 80) return;
    int r  = idx / 80;
    int c2 = (idx - r * 80) * 2;
    float a = (c2     < DIM) ? x[(size_t)r * DIM + c2]     : 0.f;
    float b = (c2 + 1 < DIM) ? x[(size_t)r * DIM + c2 + 1] : 0.f;
    Abf[idx] = packbf(a, b);
}

// ---------------- MFMA GEMM: H[M][HSTR](bf16) = A[.][YSTR](bf16) @ W ----------------
__global__ __launch_bounds__(256) void k_gemm_mfma(const unsigned short* __restrict__ A,
                                                   const unsigned short* __restrict__ Wbf,
                                                   unsigned short* __restrict__ H, int M)
{
    int wave = threadIdx.x >> 6, lane = threadIdx.x & 63;
    int quad = lane >> 4, l16 = lane & 15;
    int m = blockIdx.x * 64 + wave * 16 + l16;

    const bf16x8* Arow = (const bf16x8*)(A + (size_t)m * YSTR);
    const bf16x8* Bq   = (const bf16x8*)Wbf;

    f32x4 acc[9] = {};
#pragma unroll
    for (int kc = 0; kc < 5; kc++) {
        bf16x8 af = Arow[kc * 4 + quad];
#pragma unroll
        for (int t = 0; t < 9; t++) {
            bf16x8 bfr = Bq[(t * 5 + kc) * 64 + lane];
            acc[t] = __builtin_amdgcn_mfma_f32_16x16x32_bf16(af, bfr, acc[t], 0, 0, 0);
        }
    }

    int gr0 = blockIdx.x * 64 + wave * 16 + quad * 4;
#pragma unroll
    for (int t = 0; t < 9; t++) {
        int c = t * 16 + l16;
#pragma unroll
        for (int reg = 0; reg < 4; reg++) {
            int gr = gr0 + reg;
            if (gr < M && c < HSTR) {
                float v = (c < DIM) ? acc[t][reg] : 0.f;
                H[(size_t)gr * HSTR + c] = f2bf(v);
            }
        }
    }
}

// ---------------- fused aggregate + bias + ReLU + BN (+ optional mean-pool) ----------------
// Row layout: 34 lanes x uint2 (8B) = 136 bf16 cols; lanes>=34 clamp to lane 33's
// address (dup addrs coalesce). ONE load per edge; x16 unroll = 16 edges in flight.

template <bool FINAL>
__global__ __launch_bounds__(256) void k_agg(const unsigned short* __restrict__ h,
                                             const int* __restrict__ offs,
                                             const unsigned short* __restrict__ csr_src,
                                             const float* __restrict__ dinv,
                                             const float* __restrict__ bias,
                                             const float* __restrict__ gam,
                                             const float* __restrict__ bet,
                                             const float* __restrict__ rmean,
                                             const float* __restrict__ rvar,
                                             unsigned short* __restrict__ y,
                                             const int* __restrict__ batch,
                                             const float* __restrict__ inv_cnt,
                                             float* __restrict__ outp)
{
    int node = blockIdx.x * 4 + (threadIdx.x >> 6);
    if (node >= N_NODES) return;
    int lane = threadIdx.x & 63;
    int lc = min(lane, 33);            // clamped: lanes 34..63 mirror lane 33

    float di = dinv[node];
    uint2 p = ((const uint2*)(h + (size_t)node * HSTR))[lc];   // cols 4lc..4lc+3
    float a0 = di * blo(p.x), a1 = di * bhi(p.x);
    float a2 = di * blo(p.y), a3 = di * bhi(p.y);

    int s0 = offs[node], s1 = offs[node + 1];
    for (int k0 = s0; k0 < s1; k0 += 64) {
        int nk = min(64, s1 - k0);
        int src = 0; float w = 0.f;
        if (lane < nk) {
            src = csr_src[k0 + lane];
            w   = dinv[src];           // L2-resident 200 KB table
        }
        int j = 0;
        for (; j + 16 <= nk; j += 16) {
            int   ss[16];
            float wv[16];
#pragma unroll
            for (int u = 0; u < 16; u++) {
                ss[u] = __builtin_amdgcn_readfirstlane(__shfl(src, j + u));
                wv[u] = __shfl(w, j + u);
            }
            uint2 q[16];
#pragma unroll
            for (int u = 0; u < 16; u++)
                q[u] = ((const uint2*)(h + (size_t)ss[u] * HSTR))[lc];
#pragma unroll
            for (int u = 0; u < 16; u++) {
                a0 += wv[u] * blo(q[u].x); a1 += wv[u] * bhi(q[u].x);
                a2 += wv[u] * blo(q[u].y); a3 += wv[u] * bhi(q[u].y);
            }
        }
        for (; j < nk; j++) {
            int   s  = __builtin_amdgcn_readfirstlane(__shfl(src, j));
            float ww = __shfl(w, j);
            uint2 q = ((const uint2*)(h + (size_t)s * HSTR))[lc];
            a0 += ww * blo(q.x); a1 += ww * bhi(q.x);
            a2 += ww * blo(q.y); a3 += ww * bhi(q.y);
        }
    }

    // epilogue: lane lc owns cols 4lc..4lc+3
    float av[4] = {a0, a1, a2, a3};
    float vv[4];
    int c0 = 4 * lc;
#pragma unroll
    for (int t = 0; t < 4; t++) {
        int c = c0 + t;
        float val = 0.f;
        if (c < DIM) {
            val = di * av[t] + bias[c];
            val = fmaxf(val, 0.f);
            val = (val - rmean[c]) * (gam[c] * rsqrtf(rvar[c] + EPSV)) + bet[c];
        }
        vv[t] = val;
    }

    if (FINAL) {
        int bg = batch[node];
        float ic = inv_cnt[bg];
        if (lane < 34) {
#pragma unroll
            for (int t = 0; t < 4; t++) {
                int c = c0 + t;
                if (c < DIM) atomicAdd(&outp[(size_t)bg * DIM + c], vv[t] * ic);
            }
        }
    } else {
        uint2* yrow = (uint2*)(y + (size_t)node * YSTR);
        if (lane < 34) {
            uint2 o; o.x = packbf(vv[0], vv[1]); o.y = packbf(vv[2], vv[3]);
            yrow[lane] = o;
        } else if (lane < 40) {                  // zero-pad cols 136..159
            uint2 z; z.x = 0u; z.y = 0u;
            yrow[lane] = z;
        }
    }
}

// ---------------- launch ----------------

extern "C" void kernel_launch(void* const* d_in, const int* in_sizes, int n_in,
                              void* d_out, int out_size, void* d_ws, size_t ws_size,
                              hipStream_t stream)
{
    const float* x   = (const float*)d_in[0];
    const int*   ei  = (const int*)d_in[1];
    const int*   bat = (const int*)d_in[2];
    const float* W1  = (const float*)d_in[3];
    const float* b1  = (const float*)d_in[4];
    const float* W2  = (const float*)d_in[5];
    const float* b2  = (const float*)d_in[6];
    const float* g1  = (const float*)d_in[7];
    const float* be1 = (const float*)d_in[8];
    const float* rm1 = (const float*)d_in[9];
    const float* rv1 = (const float*)d_in[10];
    const float* g2  = (const float*)d_in[11];
    const float* be2 = (const float*)d_in[12];
    const float* rm2 = (const float*)d_in[13];
    const float* rv2 = (const float*)d_in[14];
    float* outp = (float*)d_out;
    char* ws = (char*)d_ws;

    int*   deg     = (int*)  (ws + 0);         // 200000 B
    int*   cursor  = (int*)  (ws + 200000);    // 200000 B
    int*   cnt     = (int*)  (ws + 400000);    //   8192 B
    int*   offs    = (int*)  (ws + 408192);    // 200016 B (N+1 ints)
    float* dinv    = (float*)(ws + 608208);    // 200000 B
    float* inv_cnt = (float*)(ws + 808208);    //   8192 B
    int*   bsum    = (int*)  (ws + 816400);    //   1024 B
    int*   boff    = (int*)  (ws + 817424);    //   1024 B
    unsigned short* csr_src = (unsigned short*)(ws + 818448);   // 3.2 MB
    unsigned short* Wbf1 = (unsigned short*)(ws + 4018448);     // 46080 B
    unsigned short* Wbf2 = (unsigned short*)(ws + 4064528);     // 46080 B
    unsigned short* Abf  = (unsigned short*)(ws + 4110608);     // 16015360 B (50048 x 160)
    unsigned short* Hb   = (unsigned short*)(ws + 20125968);    // 13613056 B (50048 x 136)
    unsigned short* Y1   = (unsigned short*)(ws + 33739024);    // 16015360 B (50048 x 160)

    hipMemsetAsync(ws, 0, 408192, stream);                       // deg, cursor, cnt
    hipMemsetAsync(d_out, 0, (size_t)out_size * 4, stream);

    const int* row = ei;
    const int* col = ei + N_EDGES;

    int ebl = (N_EDGES + 255) / 256;
    int nbl = (N_NODES + 255) / 256;

    k_count   <<<dim3(ebl), dim3(256), 0, stream>>>(col, bat, deg, cnt);
    k_finalize<<<dim3(nbl), dim3(256), 0, stream>>>(deg, cnt, dinv, inv_cnt);
    k_scan1   <<<dim3(nbl), dim3(256), 0, stream>>>(deg, offs, bsum);
    k_scan2   <<<dim3(1),   dim3(256), 0, stream>>>(bsum, boff, nbl);
    k_scan3   <<<dim3(nbl), dim3(256), 0, stream>>>(offs, boff);
    k_fill    <<<dim3(6256), dim3(256), 0, stream>>>(row, col, offs, cursor, csr_src);

    k_w2bf<<<dim3(90), dim3(256), 0, stream>>>(W1, Wbf1);
    k_w2bf<<<dim3(90), dim3(256), 0, stream>>>(W2, Wbf2);
    k_x2bf<<<dim3((N_NODES * 80 + 255) / 256), dim3(256), 0, stream>>>(x, (unsigned*)Abf);

    int gbl = N_ROWS / 64;   // 782
    k_gemm_mfma<<<dim3(gbl), dim3(256), 0, stream>>>(Abf, Wbf1, Hb, N_NODES);
    k_agg<false><<<dim3(N_NODES / 4), dim3(256), 0, stream>>>(Hb, offs, csr_src, dinv,
                                                              b1, g1, be1, rm1, rv1,
                                                              Y1, nullptr, nullptr, nullptr);
    k_gemm_mfma<<<dim3(gbl), dim3(256), 0, stream>>>(Y1, Wbf2, Hb, N_NODES);
    k_agg<true><<<dim3(N_NODES / 4), dim3(256), 0, stream>>>(Hb, offs, csr_src, dinv,
                                                             b2, g2, be2, rm2, rv2,
                                                             nullptr, bat, inv_cnt, outp);
}

// Round 8
// 457.323 us; speedup vs baseline: 1.2147x; 1.2147x over previous
//
#include <hip/hip_runtime.h>

#define N_NODES  50000
#define N_ROWS   50048        // padded row count (multiple of 64)
#define N_EDGES  1600000
#define N_GRAPHS 2048
#define DIM      133
#define HSTR     136          // bf16 row stride for gemm-output / agg-input buffers
#define YSTR     160          // bf16 row stride for gemm-input buffers (K padded to 160)
#define EPSV     1e-5f
#define NRANGE   8
#define RSPAN    6250         // N_NODES / NRANGE

typedef __attribute__((ext_vector_type(8))) short bf16x8;
typedef __attribute__((ext_vector_type(4))) float f32x4;

// ---- bf16 helpers (raw ushort; bf16 = top 16 bits of fp32) ----
__device__ __forceinline__ float blo(unsigned u) { return __uint_as_float(u << 16); }
__device__ __forceinline__ float bhi(unsigned u) { return __uint_as_float(u & 0xFFFF0000u); }
__device__ __forceinline__ unsigned short f2bf(float x) {
    unsigned v = __float_as_uint(x);
    return (unsigned short)((v + 0x7FFFu + ((v >> 16) & 1u)) >> 16);  // RNE
}
__device__ __forceinline__ unsigned packbf(float a, float b) {
    return (unsigned)f2bf(a) | ((unsigned)f2bf(b) << 16);
}

// ---------------- setup kernels ----------------

__global__ __launch_bounds__(256) void k_count(const int* __restrict__ col,
                                               const int* __restrict__ batch,
                                               int* __restrict__ deg,
                                               int* __restrict__ cnt)
{
    int idx = blockIdx.x * 256 + threadIdx.x;
    if (idx < N_EDGES) atomicAdd(&deg[col[idx]], 1);
    if (idx < N_NODES) atomicAdd(&cnt[batch[idx]], 1);
}

__global__ __launch_bounds__(256) void k_finalize(const int* __restrict__ deg,
                                                  const int* __restrict__ cnt,
                                                  float* __restrict__ dinv,
                                                  float* __restrict__ inv_cnt)
{
    int idx = blockIdx.x * 256 + threadIdx.x;
    if (idx < N_NODES)  dinv[idx]    = rsqrtf((float)deg[idx] + 1.0f); // +1 self loop
    if (idx < N_GRAPHS) inv_cnt[idx] = 1.0f / (float)max(cnt[idx], 1);
}

__global__ __launch_bounds__(256) void k_scan1(const int* __restrict__ deg,
                                               int* __restrict__ offs,
                                               int* __restrict__ bsum)
{
    __shared__ int sd[256];
    int t = threadIdx.x;
    int idx = blockIdx.x * 256 + t;
    int v = (idx < N_NODES) ? deg[idx] : 0;
    sd[t] = v; __syncthreads();
    for (int o = 1; o < 256; o <<= 1) {
        int add = (t >= o) ? sd[t - o] : 0;
        __syncthreads();
        sd[t] += add;
        __syncthreads();
    }
    if (idx < N_NODES) offs[idx] = sd[t] - v;
    if (t == 255) bsum[blockIdx.x] = sd[255];
}

__global__ __launch_bounds__(256) void k_scan2(const int* __restrict__ bsum,
                                               int* __restrict__ boff, int nb)
{
    __shared__ int sd[256];
    int t = threadIdx.x;
    int v = (t < nb) ? bsum[t] : 0;
    sd[t] = v; __syncthreads();
    for (int o = 1; o < 256; o <<= 1) {
        int add = (t >= o) ? sd[t - o] : 0;
        __syncthreads();
        sd[t] += add;
        __syncthreads();
    }
    boff[t] = sd[t] - v;
}

__global__ __launch_bounds__(256) void k_scan3(int* __restrict__ offs,
                                               const int* __restrict__ boff)
{
    int idx = blockIdx.x * 256 + threadIdx.x;
    if (idx < N_NODES)       offs[idx] += boff[blockIdx.x];
    else if (idx == N_NODES) offs[N_NODES] = N_EDGES;
}

// Range-partitioned CSR fill: blocks with (blockIdx&7)==r only handle dests in
// range r (6250 nodes, 400 KB csr sub-region) -> scatter stays hot in one L2
// (blockIdx%8 ~ XCD round-robin heuristic; correctness doesn't depend on it).
__global__ __launch_bounds__(256) void k_fill(const int* __restrict__ row,
                                              const int* __restrict__ col,
                                              const int* __restrict__ offs,
                                              int* __restrict__ cursor,
                                              unsigned short* __restrict__ csr_src)
{
    int r  = blockIdx.x & (NRANGE - 1);
    int bi = blockIdx.x >> 3;
    int nb = gridDim.x >> 3;
    int lo = r * RSPAN, hi = lo + RSPAN;
    for (int e = bi * 256 + threadIdx.x; e < N_EDGES; e += nb * 256) {
        int c = col[e];
        if (c >= lo && c < hi) {
            int p = offs[c] + atomicAdd(&cursor[c], 1);
            csr_src[p] = (unsigned short)row[e];
        }
    }
}

// ---- pack W (fp32 [133][133], W[k][n]) into MFMA B-fragment layout ----
__global__ __launch_bounds__(256) void k_w2bf(const float* __restrict__ W,
                                              unsigned short* __restrict__ Wbf)
{
    int idx = blockIdx.x * 256 + threadIdx.x;          // 9*5*64*8 = 23040
    if (idx >= 23040) return;
    int j    = idx & 7;
    int lane = (idx >> 3) & 63;
    int kc   = (idx >> 9) % 5;
    int t    = idx / (8 * 64 * 5);
    int k = kc * 32 + (lane >> 4) * 8 + j;
    int n = t * 16 + (lane & 15);
    float v = (k < DIM && n < DIM) ? W[k * DIM + n] : 0.f;
    Wbf[idx] = f2bf(v);
}

// ---- convert x fp32 [N][133] -> bf16 [N][160] with zero K-padding ----
__global__ __launch_bounds__(256) void k_x2bf(const float* __restrict__ x,
                                              unsigned* __restrict__ Abf) // uint = 2 bf16
{
    int idx = blockIdx.x * 256 + threadIdx.x;          // N_NODES * 80
    if (idx >= N_NODES * 80) return;
    int r  = idx / 80;
    int c2 = (idx - r * 80) * 2;
    float a = (c2     < DIM) ? x[(size_t)r * DIM + c2]     : 0.f;
    float b = (c2 + 1 < DIM) ? x[(size_t)r * DIM + c2 + 1] : 0.f;
    Abf[idx] = packbf(a, b);
}

// ---------------- MFMA GEMM: H[M][HSTR](bf16) = A[.][YSTR](bf16) @ W ----------------
__global__ __launch_bounds__(256) void k_gemm_mfma(const unsigned short* __restrict__ A,
                                                   const unsigned short* __restrict__ Wbf,
                                                   unsigned short* __restrict__ H, int M)
{
    int wave = threadIdx.x >> 6, lane = threadIdx.x & 63;
    int quad = lane >> 4, l16 = lane & 15;
    int m = blockIdx.x * 64 + wave * 16 + l16;

    const bf16x8* Arow = (const bf16x8*)(A + (size_t)m * YSTR);
    const bf16x8* Bq   = (const bf16x8*)Wbf;

    f32x4 acc[9] = {};
#pragma unroll
    for (int kc = 0; kc < 5; kc++) {
        bf16x8 af = Arow[kc * 4 + quad];
#pragma unroll
        for (int t = 0; t < 9; t++) {
            bf16x8 bfr = Bq[(t * 5 + kc) * 64 + lane];
            acc[t] = __builtin_amdgcn_mfma_f32_16x16x32_bf16(af, bfr, acc[t], 0, 0, 0);
        }
    }

    int gr0 = blockIdx.x * 64 + wave * 16 + quad * 4;
#pragma unroll
    for (int t = 0; t < 9; t++) {
        int c = t * 16 + l16;
#pragma unroll
        for (int reg = 0; reg < 4; reg++) {
            int gr = gr0 + reg;
            if (gr < M && c < HSTR) {
                float v = (c < DIM) ? acc[t][reg] : 0.f;
                H[(size_t)gr * HSTR + c] = f2bf(v);
            }
        }
    }
}

// ---------------- fused aggregate + bias + ReLU + BN (+ optional mean-pool) ----------------
// 8x-unrolled gather loop: 16 independent loads in flight per wave.
// NOTE: x16-unroll + uint2-clamped-lane variant REGRESSED (R7: VGPR 48,
// occupancy 46%, WRITE 2x) — keep this VGPR-light form.

template <bool FINAL>
__global__ __launch_bounds__(256) void k_agg(const unsigned short* __restrict__ h,
                                             const int* __restrict__ offs,
                                             const unsigned short* __restrict__ csr_src,
                                             const float* __restrict__ dinv,
                                             const float* __restrict__ bias,
                                             const float* __restrict__ gam,
                                             const float* __restrict__ bet,
                                             const float* __restrict__ rmean,
                                             const float* __restrict__ rvar,
                                             unsigned short* __restrict__ y,
                                             const int* __restrict__ batch,
                                             const float* __restrict__ inv_cnt,
                                             float* __restrict__ outp)
{
    int node = blockIdx.x * 4 + (threadIdx.x >> 6);
    if (node >= N_NODES) return;
    int lane = threadIdx.x & 63;
    int l2 = lane & 3;

    float di = dinv[node];
    const unsigned* hrow = (const unsigned*)(h + (size_t)node * HSTR);
    unsigned p0 = hrow[lane];        // cols 2*lane, 2*lane+1
    unsigned p1 = hrow[64 + l2];     // cols 128+2*l2 (dup for lanes>=4, discarded)
    float2 a0; a0.x = di * blo(p0); a0.y = di * bhi(p0);   // self-loop term
    float2 a1; a1.x = di * blo(p1); a1.y = di * bhi(p1);

    int s0 = offs[node], s1 = offs[node + 1];
    for (int k0 = s0; k0 < s1; k0 += 64) {
        int nk = min(64, s1 - k0);
        int src = 0; float w = 0.f;
        if (lane < nk) {
            src = csr_src[k0 + lane];
            w   = dinv[src];          // L2-resident 200 KB table
        }
        int j = 0;
        for (; j + 8 <= nk; j += 8) {
            int   ss[8];
            float wv[8];
#pragma unroll
            for (int u = 0; u < 8; u++) {
                ss[u] = __builtin_amdgcn_readfirstlane(__shfl(src, j + u));
                wv[u] = __shfl(w, j + u);
            }
            unsigned q0[8], q1[8];
#pragma unroll
            for (int u = 0; u < 8; u++) {
                const unsigned* r = (const unsigned*)(h + (size_t)ss[u] * HSTR);
                q0[u] = r[lane];
                q1[u] = r[64 + l2];
            }
#pragma unroll
            for (int u = 0; u < 8; u++) {
                a0.x += wv[u] * blo(q0[u]); a0.y += wv[u] * bhi(q0[u]);
                a1.x += wv[u] * blo(q1[u]); a1.y += wv[u] * bhi(q1[u]);
            }
        }
        for (; j < nk; j++) {
            int   s  = __builtin_amdgcn_readfirstlane(__shfl(src, j));
            float ww = __shfl(w, j);
            const unsigned* hr = (const unsigned*)(h + (size_t)s * HSTR);
            unsigned q0 = hr[lane];
            unsigned q1 = hr[64 + l2];
            a0.x += ww * blo(q0); a0.y += ww * bhi(q0);
            a1.x += ww * blo(q1); a1.y += ww * bhi(q1);
        }
    }

    float ic = 0.f; int bg = 0;
    if (FINAL) { bg = batch[node]; ic = inv_cnt[bg]; }

    // main pair: cols 2*lane, 2*lane+1 (both < 128 < DIM)
    {
        int c = 2 * lane;
        float va = di * a0.x + bias[c];
        va = fmaxf(va, 0.f);
        va = (va - rmean[c]) * (gam[c] * rsqrtf(rvar[c] + EPSV)) + bet[c];
        int c1 = c + 1;
        float vb = di * a0.y + bias[c1];
        vb = fmaxf(vb, 0.f);
        vb = (vb - rmean[c1]) * (gam[c1] * rsqrtf(rvar[c1] + EPSV)) + bet[c1];
        if (FINAL) {
            atomicAdd(&outp[(size_t)bg * DIM + c],  va * ic);
            atomicAdd(&outp[(size_t)bg * DIM + c1], vb * ic);
        } else {
            ((unsigned*)(y + (size_t)node * YSTR))[lane] = packbf(va, vb);
        }
    }
    // tail: cols 128..159. lanes 0-3 compute cols 128+2*l2 (masked >=133); lanes 4-15 pad zeros.
    if (lane < 16) {
        float va = 0.f, vb = 0.f;
        if (lane < 4) {
            int c = 128 + 2 * l2;
            if (c < DIM) {
                va = di * a1.x + bias[c];
                va = fmaxf(va, 0.f);
                va = (va - rmean[c]) * (gam[c] * rsqrtf(rvar[c] + EPSV)) + bet[c];
            }
            int c1 = c + 1;
            if (c1 < DIM) {
                vb = di * a1.y + bias[c1];
                vb = fmaxf(vb, 0.f);
                vb = (vb - rmean[c1]) * (gam[c1] * rsqrtf(rvar[c1] + EPSV)) + bet[c1];
            }
            if (FINAL) {
                if (c  < DIM) atomicAdd(&outp[(size_t)bg * DIM + c],  va * ic);
                if (c1 < DIM) atomicAdd(&outp[(size_t)bg * DIM + c1], vb * ic);
            }
        }
        if (!FINAL)
            ((unsigned*)(y + (size_t)node * YSTR))[64 + lane] = packbf(va, vb);
    }
}

// ---------------- launch ----------------

extern "C" void kernel_launch(void* const* d_in, const int* in_sizes, int n_in,
                              void* d_out, int out_size, void* d_ws, size_t ws_size,
                              hipStream_t stream)
{
    const float* x   = (const float*)d_in[0];
    const int*   ei  = (const int*)d_in[1];
    const int*   bat = (const int*)d_in[2];
    const float* W1  = (const float*)d_in[3];
    const float* b1  = (const float*)d_in[4];
    const float* W2  = (const float*)d_in[5];
    const float* b2  = (const float*)d_in[6];
    const float* g1  = (const float*)d_in[7];
    const float* be1 = (const float*)d_in[8];
    const float* rm1 = (const float*)d_in[9];
    const float* rv1 = (const float*)d_in[10];
    const float* g2  = (const float*)d_in[11];
    const float* be2 = (const float*)d_in[12];
    const float* rm2 = (const float*)d_in[13];
    const float* rv2 = (const float*)d_in[14];
    float* outp = (float*)d_out;
    char* ws = (char*)d_ws;

    int*   deg     = (int*)  (ws + 0);         // 200000 B
    int*   cursor  = (int*)  (ws + 200000);    // 200000 B
    int*   cnt     = (int*)  (ws + 400000);    //   8192 B
    int*   offs    = (int*)  (ws + 408192);    // 200016 B (N+1 ints)
    float* dinv    = (float*)(ws + 608208);    // 200000 B
    float* inv_cnt = (float*)(ws + 808208);    //   8192 B
    int*   bsum    = (int*)  (ws + 816400);    //   1024 B
    int*   boff    = (int*)  (ws + 817424);    //   1024 B
    unsigned short* csr_src = (unsigned short*)(ws + 818448);   // 3.2 MB
    unsigned short* Wbf1 = (unsigned short*)(ws + 4018448);     // 46080 B
    unsigned short* Wbf2 = (unsigned short*)(ws + 4064528);     // 46080 B
    unsigned short* Abf  = (unsigned short*)(ws + 4110608);     // 16015360 B (50048 x 160)
    unsigned short* Hb   = (unsigned short*)(ws + 20125968);    // 13613056 B (50048 x 136)
    unsigned short* Y1   = (unsigned short*)(ws + 33739024);    // 16015360 B (50048 x 160)

    hipMemsetAsync(ws, 0, 408192, stream);                       // deg, cursor, cnt
    hipMemsetAsync(d_out, 0, (size_t)out_size * 4, stream);

    const int* row = ei;
    const int* col = ei + N_EDGES;

    int ebl = (N_EDGES + 255) / 256;
    int nbl = (N_NODES + 255) / 256;

    k_count   <<<dim3(ebl), dim3(256), 0, stream>>>(col, bat, deg, cnt);
    k_finalize<<<dim3(nbl), dim3(256), 0, stream>>>(deg, cnt, dinv, inv_cnt);
    k_scan1   <<<dim3(nbl), dim3(256), 0, stream>>>(deg, offs, bsum);
    k_scan2   <<<dim3(1),   dim3(256), 0, stream>>>(bsum, boff, nbl);
    k_scan3   <<<dim3(nbl), dim3(256), 0, stream>>>(offs, boff);
    k_fill    <<<dim3(6256), dim3(256), 0, stream>>>(row, col, offs, cursor, csr_src);

    k_w2bf<<<dim3(90), dim3(256), 0, stream>>>(W1, Wbf1);
    k_w2bf<<<dim3(90), dim3(256), 0, stream>>>(W2, Wbf2);
    k_x2bf<<<dim3((N_NODES * 80 + 255) / 256), dim3(256), 0, stream>>>(x, (unsigned*)Abf);

    int gbl = N_ROWS / 64;   // 782
    k_gemm_mfma<<<dim3(gbl), dim3(256), 0, stream>>>(Abf, Wbf1, Hb, N_NODES);
    k_agg<false><<<dim3(N_NODES / 4), dim3(256), 0, stream>>>(Hb, offs, csr_src, dinv,
                                                              b1, g1, be1, rm1, rv1,
                                                              Y1, nullptr, nullptr, nullptr);
    k_gemm_mfma<<<dim3(gbl), dim3(256), 0, stream>>>(Y1, Wbf2, Hb, N_NODES);
    k_agg<true><<<dim3(N_NODES / 4), dim3(256), 0, stream>>>(Hb, offs, csr_src, dinv,
                                                             b2, g2, be2, rm2, rv2,
                                                             nullptr, bat, inv_cnt, outp);
}